// Round 7
// baseline (251.544 us; speedup 1.0000x reference)
//
#include <hip/hip_runtime.h>

#define CIN 128
#define COUT 256
#define IH 96
#define IW 96
#define NB 8
#define HW (IH*IW)          // 9216
#define NPIX (NB*HW)        // 73728
#define BLK_PER_IMG (HW/64) // 144
#define TBLK (NPIX/64)      // 1152 transpose blocks
#define ALD_CS 528          // shorts per chunk-plane (264 dwords = 256 + 8 pad)
#define ALD_BUF (16*ALD_CS) // 8448 shorts per A-buffer (16896 B)

typedef __attribute__((ext_vector_type(8))) short short8;
typedef __attribute__((ext_vector_type(4))) float floatx4;

static __device__ __forceinline__ short f2bf(float f) {
  unsigned int u = __builtin_bit_cast(unsigned int, f);
  u = u + 0x7fffu + ((u >> 16) & 1u);
  return (short)(u >> 16);
}
static __device__ __forceinline__ float bf2f(short s) {
  unsigned int u = ((unsigned int)(unsigned short)s) << 16;
  return __builtin_bit_cast(float, u);
}

struct Corner {
  float w00, w01, w10, w11;
  const short *r00, *r01, *r10, *r11;
};

static __device__ __forceinline__ Corner corner_setup(float py, float px, float mk,
                                                      const short* xtb, int choff) {
  Corner c;
  float y0f = floorf(py), x0f = floorf(px);
  float wy1 = py - y0f, wx1 = px - x0f;
  float wy0 = 1.f - wy1, wx0 = 1.f - wx1;
  bool vy0 = (y0f >= 0.f) && (y0f <= (float)(IH - 1));
  bool vy1 = (y0f + 1.f >= 0.f) && (y0f + 1.f <= (float)(IH - 1));
  bool vx0 = (x0f >= 0.f) && (x0f <= (float)(IW - 1));
  bool vx1 = (x0f + 1.f >= 0.f) && (x0f + 1.f <= (float)(IW - 1));
  int iy0 = min(max((int)y0f, 0), IH - 1);
  int iy1 = min(max((int)y0f + 1, 0), IH - 1);
  int ix0 = min(max((int)x0f, 0), IW - 1);
  int ix1 = min(max((int)x0f + 1, 0), IW - 1);
  c.w00 = wy0 * wx0 * mk * ((vy0 && vx0) ? 1.f : 0.f);
  c.w01 = wy0 * wx1 * mk * ((vy0 && vx1) ? 1.f : 0.f);
  c.w10 = wy1 * wx0 * mk * ((vy1 && vx0) ? 1.f : 0.f);
  c.w11 = wy1 * wx1 * mk * ((vy1 && vx1) ? 1.f : 0.f);
  c.r00 = xtb + (size_t)(iy0 * IW + ix0) * 128 + choff;
  c.r01 = xtb + (size_t)(iy0 * IW + ix1) * 128 + choff;
  c.r10 = xtb + (size_t)(iy1 * IW + ix0) * 128 + choff;
  c.r11 = xtb + (size_t)(iy1 * IW + ix1) * 128 + choff;
  return c;
}

static __device__ __forceinline__ short8 interp8(short8 s00, short8 s01,
                                                 short8 s10, short8 s11,
                                                 const Corner& c) {
  short8 o;
  #pragma unroll
  for (int j = 0; j < 8; ++j) {
    float v = c.w00 * bf2f(s00[j]) + c.w01 * bf2f(s01[j])
            + c.w10 * bf2f(s10[j]) + c.w11 * bf2f(s11[j]);
    o[j] = f2bf(v);
  }
  return o;
}

// ---------------------------------------------------------------------------
// Kernel 0 (fused prep + transpose, unchanged from R5).
// ---------------------------------------------------------------------------
__global__ __launch_bounds__(256, 8)
void prep_and_transpose(const float* __restrict__ x, short* __restrict__ xt,
                        const float* __restrict__ weight,
                        const float* __restrict__ offset_w,
                        const float* __restrict__ mask_w,
                        short* __restrict__ Bt2f, short* __restrict__ Bt1f) {
  const int blk = blockIdx.x;
  const int tid = threadIdx.x;

  if (blk >= TBLK) {
    const int n2 = 9 * 4 * 16 * 512;        // 294912
    int base = (blk - TBLK) * 1024 + tid;
    #pragma unroll
    for (int k = 0; k < 4; ++k) {
      int idx = base + k * 256;
      if (idx < n2) {
        int e = idx & 7, lane = (idx >> 3) & 63;
        int g = idx >> 9;
        int nl = g & 15, kq = (g >> 4) & 3, tap = g >> 6;
        int o = nl * 16 + (lane & 15);
        int c = kq * 32 + (lane >> 4) * 8 + e;
        Bt2f[idx] = f2bf(weight[(o * CIN + c) * 9 + tap]);
      } else {
        int j = idx - n2;                   // < 36864 by construction
        int e = j & 7, lane = (j >> 3) & 63;
        int g = j >> 9;
        int nl = g & 1, kq = (g >> 1) & 3, tap = g >> 3;
        int n = nl * 16 + (lane & 15);
        int c = kq * 32 + (lane >> 4) * 8 + e;
        float v = 0.f;
        if (n < 27)
          v = (n < 18) ? offset_w[(n * CIN + c) * 9 + tap]
                       : mask_w[((n - 18) * CIN + c) * 9 + tap];
        Bt1f[j] = f2bf(v);
      }
    }
    return;
  }

  __shared__ short tile[64 * 130];
  const int p0  = blk * 64;
  const int b   = p0 / HW;
  const int hw0 = p0 % HW;
  const float* xb = x + (size_t)b * CIN * HW + hw0;

  const int pq = tid & 15;                  // pixel quad (4*pq .. 4*pq+3)
  const int cg = tid >> 4;                  // channel-pair group (0..15)

  #pragma unroll
  for (int r = 0; r < 4; ++r) {
    const int c = r * 32 + cg * 2;
    float4 v0 = *(const float4*)(xb + (size_t)c * HW + 4 * pq);
    float4 v1 = *(const float4*)(xb + (size_t)(c + 1) * HW + 4 * pq);
    unsigned int d0 = (unsigned short)f2bf(v0.x) | ((unsigned int)(unsigned short)f2bf(v1.x) << 16);
    unsigned int d1 = (unsigned short)f2bf(v0.y) | ((unsigned int)(unsigned short)f2bf(v1.y) << 16);
    unsigned int d2 = (unsigned short)f2bf(v0.z) | ((unsigned int)(unsigned short)f2bf(v1.z) << 16);
    unsigned int d3 = (unsigned short)f2bf(v0.w) | ((unsigned int)(unsigned short)f2bf(v1.w) << 16);
    *(unsigned int*)(&tile[(4 * pq + 0) * 130 + c]) = d0;
    *(unsigned int*)(&tile[(4 * pq + 1) * 130 + c]) = d1;
    *(unsigned int*)(&tile[(4 * pq + 2) * 130 + c]) = d2;
    *(unsigned int*)(&tile[(4 * pq + 3) * 130 + c]) = d3;
  }
  __syncthreads();

  unsigned int* dst = (unsigned int*)(xt + ((size_t)b * HW + hw0) * 128);
  #pragma unroll
  for (int i = 0; i < 4; ++i) {
    int gidx = i * 1024 + tid * 4;
    int px = gidx >> 6, cw0 = gidx & 63;
    uint4 w;
    w.x = *(const unsigned int*)(&tile[px * 130 + 2 * (cw0 + 0)]);
    w.y = *(const unsigned int*)(&tile[px * 130 + 2 * (cw0 + 1)]);
    w.z = *(const unsigned int*)(&tile[px * 130 + 2 * (cw0 + 2)]);
    w.w = *(const unsigned int*)(&tile[px * 130 + 2 * (cw0 + 3)]);
    *(uint4*)(dst + gidx) = w;
  }
}

// ---------------------------------------------------------------------------
// Kernel 1 (R6): fused offmask prologue + deform GEMM.
//  LDS layout change: CHUNK-MAJOR A-tiles, A[s=0..15][264 dwords] per buffer
//  (8-dword pad per plane).  Bank quad for reads = (m+2q)%8, for writes =
//  (r8+2ck)%8 -- both exactly uniform (8 lanes/quad = minimum), so the XOR
//  swizzle is gone.  Ald 34816->33792 B, pmb col-major [64][27] 6912 B:
//  block total 40704 -> 40960 padded = exactly 160KiB/4 => 4 blocks/CU
//  (launch_bounds(256,4); was 3 at 25% occupancy).
//  Prologue rebuilt cooperatively: A staged through LDS with the 8-lanes-
//  per-pixel mapping (8 cache lines/instr vs 16), double-buffered across the
//  two Ald planes, next-tap loads issued before this tap's MFMAs.
// ---------------------------------------------------------------------------
__global__ __launch_bounds__(256, 4)
void deform_main(const short* __restrict__ xt,
                 const short* __restrict__ Bt2f,
                 const short* __restrict__ Bt1f,
                 const float* __restrict__ offset_b,
                 const float* __restrict__ mask_b,
                 const float* __restrict__ bias,
                 float* __restrict__ out) {
  __shared__ short Ald[2 * ALD_BUF];        // 33792 B
  __shared__ float pmb[64 * 27];            //  6912 B, pmb[col*27 + idx]

  const int tid  = threadIdx.x;
  const int lane = tid & 63;
  const int wv   = tid >> 6;
  const int q    = lane >> 4;
  const int m    = lane & 15;
  const int r8   = lane >> 3;               // pixel within group of 8
  const int ck   = lane & 7;                // 16B chunk within 128B half-row
  const int ckoff = ck * 8;                 // shorts, folded into row ptrs
  const int blk  = blockIdx.x;
  const int l    = (blk & 7) * BLK_PER_IMG + (blk >> 3);
  const int p0   = l * 64;
  const int b    = p0 / HW;
  const short* xtb = xt + (size_t)b * HW * 128;

  const int row0 = wv * 16 + r8;            // this thread's staging rows
  const int row1 = row0 + 8;

  // per-pixel coords (prologue taps)
  const int hw0p = (p0 + row0) % HW;
  const int h0p  = hw0p / IW, w0p = hw0p % IW;
  const int hw1p = (p0 + row1) % HW;
  const int h1p  = hw1p / IW, w1p = hw1p % IW;

  // ===== PROLOGUE: offset/mask conv, cooperative A-staging via LDS =====
  {
    const short8 z = (short8){0, 0, 0, 0, 0, 0, 0, 0};
    floatx4 acc0 = (floatx4){0.f, 0.f, 0.f, 0.f};
    floatx4 acc1 = (floatx4){0.f, 0.f, 0.f, 0.f};
    short8 P0, P1, P2, P3;

    auto ldtap = [&](int tap, short8& A0, short8& A1, short8& B0, short8& B1) {
      const int kh = tap / 3, kw = tap % 3;
      int iy = h0p + kh - 1, ix = w0p + kw - 1;
      bool v = (iy >= 0) && (iy < IH) && (ix >= 0) && (ix < IW);
      const short* s = xtb + (v ? (size_t)(iy * IW + ix) * 128 : 0) + ckoff;
      A0 = *(const short8*)(s);
      A1 = *(const short8*)(s + 64);
      if (!v) { A0 = z; A1 = z; }
      iy = h1p + kh - 1; ix = w1p + kw - 1;
      bool v2 = (iy >= 0) && (iy < IH) && (ix >= 0) && (ix < IW);
      const short* s2 = xtb + (v2 ? (size_t)(iy * IW + ix) * 128 : 0) + ckoff;
      B0 = *(const short8*)(s2);
      B1 = *(const short8*)(s2 + 64);
      if (!v2) { B0 = z; B1 = z; }
    };
    auto sttap = [&](short* buf, short8 A0, short8 A1, short8 B0, short8 B1) {
      *(short8*)(&buf[ck * ALD_CS + row0 * 8])       = A0;
      *(short8*)(&buf[(ck + 8) * ALD_CS + row0 * 8]) = A1;
      *(short8*)(&buf[ck * ALD_CS + row1 * 8])       = B0;
      *(short8*)(&buf[(ck + 8) * ALD_CS + row1 * 8]) = B1;
    };

    ldtap(0, P0, P1, P2, P3);
    sttap(Ald, P0, P1, P2, P3);
    __syncthreads();

    for (int tap = 0; tap < 9; ++tap) {
      const short* rb = Ald + (tap & 1) * ALD_BUF;
      short* const wb2 = Ald + ((tap & 1) ^ 1) * ALD_BUF;
      if (tap < 8) ldtap(tap + 1, P0, P1, P2, P3);

      short8 bb0[4], bb1[4];
      #pragma unroll
      for (int kq = 0; kq < 4; ++kq) {
        bb0[kq] = *(const short8*)(Bt1f + (size_t)((tap * 4 + kq) * 2 + 0) * 512 + lane * 8);
        bb1[kq] = *(const short8*)(Bt1f + (size_t)((tap * 4 + kq) * 2 + 1) * 512 + lane * 8);
      }
      short8 a[4];
      #pragma unroll
      for (int kq = 0; kq < 4; ++kq)
        a[kq] = *(const short8*)(&rb[(kq * 4 + q) * ALD_CS + (wv * 16 + m) * 8]);
      #pragma unroll
      for (int kq = 0; kq < 4; ++kq) {
        acc0 = __builtin_amdgcn_mfma_f32_16x16x32_bf16(a[kq], bb0[kq], acc0, 0, 0, 0);
        acc1 = __builtin_amdgcn_mfma_f32_16x16x32_bf16(a[kq], bb1[kq], acc1, 0, 0, 0);
      }
      if (tap < 8) sttap(wb2, P0, P1, P2, P3);
      __syncthreads();
    }

    #pragma unroll
    for (int nl = 0; nl < 2; ++nl) {
      floatx4 ac = nl ? acc1 : acc0;
      int chn = nl * 16 + m;
      if (chn < 18) {
        int tap = chn >> 1, plane = chn & 1;
        float cb = offset_b[chn];
        #pragma unroll
        for (int r = 0; r < 4; ++r) {
          int col = wv * 16 + q * 4 + r;
          int hwp = (p0 + col) % HW;
          float base = plane ? (float)(hwp % IW + tap % 3 - 1)
                             : (float)(hwp / IW + tap / 3 - 1);
          pmb[col * 27 + plane * 9 + tap] = ac[r] + cb + base;
        }
      } else if (chn < 27) {
        int tap = chn - 18;
        float cb = mask_b[tap];
        #pragma unroll
        for (int r = 0; r < 4; ++r) {
          int col = wv * 16 + q * 4 + r;
          float v = ac[r] + cb;
          pmb[col * 27 + 18 + tap] = 1.f / (1.f + expf(-v));
        }
      }
    }
  }
  __syncthreads();

  // ===== MAIN: cooperative-gather sampling + deformable GEMM =====
  floatx4 acc[4][4];
  #pragma unroll
  for (int i = 0; i < 4; ++i)
    #pragma unroll
    for (int j = 0; j < 4; ++j) acc[i][j] = (floatx4){0.f, 0.f, 0.f, 0.f};

  // ---- stage tap 0 (cooperative) ----
  {
    float py0 = pmb[row0 * 27 + 0], px0 = pmb[row0 * 27 + 9], mk0 = pmb[row0 * 27 + 18];
    float py1 = pmb[row1 * 27 + 0], px1 = pmb[row1 * 27 + 9], mk1 = pmb[row1 * 27 + 18];
    Corner c0 = corner_setup(py0, px0, mk0, xtb, ckoff);
    Corner c1 = corner_setup(py1, px1, mk1, xtb, ckoff);
    short8 a0 = *(const short8*)(c0.r00),      a1 = *(const short8*)(c0.r01);
    short8 a2 = *(const short8*)(c0.r10),      a3 = *(const short8*)(c0.r11);
    short8 a4 = *(const short8*)(c0.r00 + 64), a5 = *(const short8*)(c0.r01 + 64);
    short8 a6 = *(const short8*)(c0.r10 + 64), a7 = *(const short8*)(c0.r11 + 64);
    short8 b0 = *(const short8*)(c1.r00),      b1 = *(const short8*)(c1.r01);
    short8 b2 = *(const short8*)(c1.r10),      b3 = *(const short8*)(c1.r11);
    short8 b4 = *(const short8*)(c1.r00 + 64), b5 = *(const short8*)(c1.r01 + 64);
    short8 b6 = *(const short8*)(c1.r10 + 64), b7 = *(const short8*)(c1.r11 + 64);
    *(short8*)(&Ald[ck * ALD_CS + row0 * 8])       = interp8(a0, a1, a2, a3, c0);
    *(short8*)(&Ald[(ck + 8) * ALD_CS + row0 * 8]) = interp8(a4, a5, a6, a7, c0);
    *(short8*)(&Ald[ck * ALD_CS + row1 * 8])       = interp8(b0, b1, b2, b3, c1);
    *(short8*)(&Ald[(ck + 8) * ALD_CS + row1 * 8]) = interp8(b4, b5, b6, b7, c1);
  }
  float pyN0 = pmb[row0 * 27 + 1], pxN0 = pmb[row0 * 27 + 10], mkN0 = pmb[row0 * 27 + 19];
  float pyN1 = pmb[row1 * 27 + 1], pxN1 = pmb[row1 * 27 + 10], mkN1 = pmb[row1 * 27 + 19];
  __syncthreads();

  for (int tap = 0; tap < 9; ++tap) {
    const short* bufr = Ald + (tap & 1) * ALD_BUF;
    short* const bufw = Ald + ((tap & 1) ^ 1) * ALD_BUF;
    const bool nxt = (tap < 8);

    Corner c0, c1;
    if (nxt) {
      c0 = corner_setup(pyN0, pxN0, mkN0, xtb, ckoff);
      c1 = corner_setup(pyN1, pxN1, mkN1, xtb, ckoff);
    }
    if (tap < 7) {
      pyN0 = pmb[row0 * 27 + tap + 2];
      pxN0 = pmb[row0 * 27 + tap + 11];
      mkN0 = pmb[row0 * 27 + tap + 20];
      pyN1 = pmb[row1 * 27 + tap + 2];
      pxN1 = pmb[row1 * 27 + tap + 11];
      mkN1 = pmb[row1 * 27 + tap + 20];
    }

    // ---- B-frags kq0,kq1 + pixel-group-0 gathers in flight over kq0/kq1
    short8 bfA[4], bfB[4];
    #pragma unroll
    for (int nl = 0; nl < 4; ++nl) {
      bfA[nl] = *(const short8*)(Bt2f + (size_t)((tap * 4 + 0) * 16 + wv * 4 + nl) * 512 + lane * 8);
      bfB[nl] = *(const short8*)(Bt2f + (size_t)((tap * 4 + 1) * 16 + wv * 4 + nl) * 512 + lane * 8);
    }
    short8 g0, g1, g2, g3, g4, g5, g6, g7;
    if (nxt) {
      g0 = *(const short8*)(c0.r00);      g1 = *(const short8*)(c0.r01);
      g2 = *(const short8*)(c0.r10);      g3 = *(const short8*)(c0.r11);
      g4 = *(const short8*)(c0.r00 + 64); g5 = *(const short8*)(c0.r01 + 64);
      g6 = *(const short8*)(c0.r10 + 64); g7 = *(const short8*)(c0.r11 + 64);
    }
    // kq0
    {
      short8 af[4];
      #pragma unroll
      for (int mt = 0; mt < 4; ++mt)
        af[mt] = *(const short8*)(&bufr[(0 * 4 + q) * ALD_CS + (mt * 16 + m) * 8]);
      #pragma unroll
      for (int mt = 0; mt < 4; ++mt)
        #pragma unroll
        for (int nl = 0; nl < 4; ++nl)
          acc[mt][nl] = __builtin_amdgcn_mfma_f32_16x16x32_bf16(af[mt], bfA[nl], acc[mt][nl], 0, 0, 0);
    }
    // kq1
    {
      short8 af[4];
      #pragma unroll
      for (int mt = 0; mt < 4; ++mt)
        af[mt] = *(const short8*)(&bufr[(1 * 4 + q) * ALD_CS + (mt * 16 + m) * 8]);
      #pragma unroll
      for (int mt = 0; mt < 4; ++mt)
        #pragma unroll
        for (int nl = 0; nl < 4; ++nl)
          acc[mt][nl] = __builtin_amdgcn_mfma_f32_16x16x32_bf16(af[mt], bfB[nl], acc[mt][nl], 0, 0, 0);
    }
    // ---- B-frags kq2,kq3; interp pg0; pg1 gathers in flight over kq2/kq3
    short8 bfC[4], bfD[4];
    #pragma unroll
    for (int nl = 0; nl < 4; ++nl) {
      bfC[nl] = *(const short8*)(Bt2f + (size_t)((tap * 4 + 2) * 16 + wv * 4 + nl) * 512 + lane * 8);
      bfD[nl] = *(const short8*)(Bt2f + (size_t)((tap * 4 + 3) * 16 + wv * 4 + nl) * 512 + lane * 8);
    }
    if (nxt) {
      *(short8*)(&bufw[ck * ALD_CS + row0 * 8])       = interp8(g0, g1, g2, g3, c0);
      *(short8*)(&bufw[(ck + 8) * ALD_CS + row0 * 8]) = interp8(g4, g5, g6, g7, c0);
      g0 = *(const short8*)(c1.r00);      g1 = *(const short8*)(c1.r01);
      g2 = *(const short8*)(c1.r10);      g3 = *(const short8*)(c1.r11);
      g4 = *(const short8*)(c1.r00 + 64); g5 = *(const short8*)(c1.r01 + 64);
      g6 = *(const short8*)(c1.r10 + 64); g7 = *(const short8*)(c1.r11 + 64);
    }
    // kq2
    {
      short8 af[4];
      #pragma unroll
      for (int mt = 0; mt < 4; ++mt)
        af[mt] = *(const short8*)(&bufr[(2 * 4 + q) * ALD_CS + (mt * 16 + m) * 8]);
      #pragma unroll
      for (int mt = 0; mt < 4; ++mt)
        #pragma unroll
        for (int nl = 0; nl < 4; ++nl)
          acc[mt][nl] = __builtin_amdgcn_mfma_f32_16x16x32_bf16(af[mt], bfC[nl], acc[mt][nl], 0, 0, 0);
    }
    // kq3
    {
      short8 af[4];
      #pragma unroll
      for (int mt = 0; mt < 4; ++mt)
        af[mt] = *(const short8*)(&bufr[(3 * 4 + q) * ALD_CS + (mt * 16 + m) * 8]);
      #pragma unroll
      for (int mt = 0; mt < 4; ++mt)
        #pragma unroll
        for (int nl = 0; nl < 4; ++nl)
          acc[mt][nl] = __builtin_amdgcn_mfma_f32_16x16x32_bf16(af[mt], bfD[nl], acc[mt][nl], 0, 0, 0);
    }
    if (nxt) {
      *(short8*)(&bufw[ck * ALD_CS + row1 * 8])       = interp8(g0, g1, g2, g3, c1);
      *(short8*)(&bufw[(ck + 8) * ALD_CS + row1 * 8]) = interp8(g4, g5, g6, g7, c1);
      __syncthreads();
    }
  }

  // ---- epilogue: direct stores.  D: row=q*4+r -> px mt*16+q*4+r, col=m ----
  const int hw0 = p0 % HW;
  #pragma unroll
  for (int nl = 0; nl < 4; ++nl) {
    const int o = wv * 64 + nl * 16 + m;
    const float bs = bias[o];
    float* op = out + (size_t)(b * COUT + o) * HW + hw0;
    #pragma unroll
    for (int mt = 0; mt < 4; ++mt) {
      floatx4 v = acc[mt][nl];
      v[0] += bs; v[1] += bs; v[2] += bs; v[3] += bs;
      *(floatx4*)(op + mt * 16 + q * 4) = v;
    }
  }
}

// ---------------------------------------------------------------------------
extern "C" void kernel_launch(void* const* d_in, const int* in_sizes, int n_in,
                              void* d_out, int out_size, void* d_ws, size_t ws_size,
                              hipStream_t stream) {
  const float* x        = (const float*)d_in[0];
  const float* offset_w = (const float*)d_in[1];
  const float* offset_b = (const float*)d_in[2];
  const float* mask_w   = (const float*)d_in[3];
  const float* mask_b   = (const float*)d_in[4];
  const float* weight   = (const float*)d_in[5];
  const float* bias     = (const float*)d_in[6];
  float* out = (float*)d_out;

  char* ws = (char*)d_ws;
  const size_t XT_BYTES  = (size_t)NPIX * 128 * 2;        // 18,874,368
  const size_t BT2_BYTES = (size_t)9 * 4 * 16 * 512 * 2;  //    589,824
  short* xtp  = (short*)ws;
  short* Bt2f = (short*)(ws + XT_BYTES);
  short* Bt1f = (short*)(ws + XT_BYTES + BT2_BYTES);

  prep_and_transpose<<<dim3(TBLK + 324), dim3(256), 0, stream>>>(
      x, xtp, weight, offset_w, mask_w, Bt2f, Bt1f);
  deform_main<<<dim3(NPIX / 64), dim3(256), 0, stream>>>(
      xtp, Bt2f, Bt1f, offset_b, mask_b, bias, out);
}

// Round 8
// 216.223 us; speedup vs baseline: 1.1634x; 1.1634x over previous
//
#include <hip/hip_runtime.h>

#define CIN 128
#define COUT 256
#define IH 96
#define IW 96
#define NB 8
#define HW (IH*IW)          // 9216
#define NPIX (NB*HW)        // 73728
#define AST 136             // LDS A-tile row stride (shorts), 17 x 16B chunks
#define BLK_PER_IMG (HW/64) // 144
#define TBLK (NPIX/64)      // 1152 transpose blocks

typedef __attribute__((ext_vector_type(8))) short short8;
typedef __attribute__((ext_vector_type(4))) float floatx4;

static __device__ __forceinline__ short f2bf(float f) {
  unsigned int u = __builtin_bit_cast(unsigned int, f);
  u = u + 0x7fffu + ((u >> 16) & 1u);
  return (short)(u >> 16);
}
static __device__ __forceinline__ float bf2f(short s) {
  unsigned int u = ((unsigned int)(unsigned short)s) << 16;
  return __builtin_bit_cast(float, u);
}

struct Corner {
  float w00, w01, w10, w11;
  const short *r00, *r01, *r10, *r11;
};

static __device__ __forceinline__ Corner corner_setup(float py, float px, float mk,
                                                      const short* xtb, int choff) {
  Corner c;
  float y0f = floorf(py), x0f = floorf(px);
  float wy1 = py - y0f, wx1 = px - x0f;
  float wy0 = 1.f - wy1, wx0 = 1.f - wx1;
  bool vy0 = (y0f >= 0.f) && (y0f <= (float)(IH - 1));
  bool vy1 = (y0f + 1.f >= 0.f) && (y0f + 1.f <= (float)(IH - 1));
  bool vx0 = (x0f >= 0.f) && (x0f <= (float)(IW - 1));
  bool vx1 = (x0f + 1.f >= 0.f) && (x0f + 1.f <= (float)(IW - 1));
  int iy0 = min(max((int)y0f, 0), IH - 1);
  int iy1 = min(max((int)y0f + 1, 0), IH - 1);
  int ix0 = min(max((int)x0f, 0), IW - 1);
  int ix1 = min(max((int)x0f + 1, 0), IW - 1);
  c.w00 = wy0 * wx0 * mk * ((vy0 && vx0) ? 1.f : 0.f);
  c.w01 = wy0 * wx1 * mk * ((vy0 && vx1) ? 1.f : 0.f);
  c.w10 = wy1 * wx0 * mk * ((vy1 && vx0) ? 1.f : 0.f);
  c.w11 = wy1 * wx1 * mk * ((vy1 && vx1) ? 1.f : 0.f);
  c.r00 = xtb + (size_t)(iy0 * IW + ix0) * 128 + choff;
  c.r01 = xtb + (size_t)(iy0 * IW + ix1) * 128 + choff;
  c.r10 = xtb + (size_t)(iy1 * IW + ix0) * 128 + choff;
  c.r11 = xtb + (size_t)(iy1 * IW + ix1) * 128 + choff;
  return c;
}

static __device__ __forceinline__ short8 interp8(short8 s00, short8 s01,
                                                 short8 s10, short8 s11,
                                                 const Corner& c) {
  short8 o;
  #pragma unroll
  for (int j = 0; j < 8; ++j) {
    float v = c.w00 * bf2f(s00[j]) + c.w01 * bf2f(s01[j])
            + c.w10 * bf2f(s10[j]) + c.w11 * bf2f(s11[j]);
    o[j] = f2bf(v);
  }
  return o;
}

// ---------------------------------------------------------------------------
// Kernel 0 (fused prep + transpose, unchanged from R5 — verified).
// ---------------------------------------------------------------------------
__global__ __launch_bounds__(256, 8)
void prep_and_transpose(const float* __restrict__ x, short* __restrict__ xt,
                        const float* __restrict__ weight,
                        const float* __restrict__ offset_w,
                        const float* __restrict__ mask_w,
                        short* __restrict__ Bt2f, short* __restrict__ Bt1f) {
  const int blk = blockIdx.x;
  const int tid = threadIdx.x;

  if (blk >= TBLK) {
    const int n2 = 9 * 4 * 16 * 512;        // 294912
    int base = (blk - TBLK) * 1024 + tid;
    #pragma unroll
    for (int k = 0; k < 4; ++k) {
      int idx = base + k * 256;
      if (idx < n2) {
        int e = idx & 7, lane = (idx >> 3) & 63;
        int g = idx >> 9;
        int nl = g & 15, kq = (g >> 4) & 3, tap = g >> 6;
        int o = nl * 16 + (lane & 15);
        int c = kq * 32 + (lane >> 4) * 8 + e;
        Bt2f[idx] = f2bf(weight[(o * CIN + c) * 9 + tap]);
      } else {
        int j = idx - n2;                   // < 36864 by construction
        int e = j & 7, lane = (j >> 3) & 63;
        int g = j >> 9;
        int nl = g & 1, kq = (g >> 1) & 3, tap = g >> 3;
        int n = nl * 16 + (lane & 15);
        int c = kq * 32 + (lane >> 4) * 8 + e;
        float v = 0.f;
        if (n < 27)
          v = (n < 18) ? offset_w[(n * CIN + c) * 9 + tap]
                       : mask_w[((n - 18) * CIN + c) * 9 + tap];
        Bt1f[j] = f2bf(v);
      }
    }
    return;
  }

  __shared__ short tile[64 * 130];
  const int p0  = blk * 64;
  const int b   = p0 / HW;
  const int hw0 = p0 % HW;
  const float* xb = x + (size_t)b * CIN * HW + hw0;

  const int pq = tid & 15;                  // pixel quad (4*pq .. 4*pq+3)
  const int cg = tid >> 4;                  // channel-pair group (0..15)

  #pragma unroll
  for (int r = 0; r < 4; ++r) {
    const int c = r * 32 + cg * 2;
    float4 v0 = *(const float4*)(xb + (size_t)c * HW + 4 * pq);
    float4 v1 = *(const float4*)(xb + (size_t)(c + 1) * HW + 4 * pq);
    unsigned int d0 = (unsigned short)f2bf(v0.x) | ((unsigned int)(unsigned short)f2bf(v1.x) << 16);
    unsigned int d1 = (unsigned short)f2bf(v0.y) | ((unsigned int)(unsigned short)f2bf(v1.y) << 16);
    unsigned int d2 = (unsigned short)f2bf(v0.z) | ((unsigned int)(unsigned short)f2bf(v1.z) << 16);
    unsigned int d3 = (unsigned short)f2bf(v0.w) | ((unsigned int)(unsigned short)f2bf(v1.w) << 16);
    *(unsigned int*)(&tile[(4 * pq + 0) * 130 + c]) = d0;
    *(unsigned int*)(&tile[(4 * pq + 1) * 130 + c]) = d1;
    *(unsigned int*)(&tile[(4 * pq + 2) * 130 + c]) = d2;
    *(unsigned int*)(&tile[(4 * pq + 3) * 130 + c]) = d3;
  }
  __syncthreads();

  unsigned int* dst = (unsigned int*)(xt + ((size_t)b * HW + hw0) * 128);
  #pragma unroll
  for (int i = 0; i < 4; ++i) {
    int gidx = i * 1024 + tid * 4;
    int px = gidx >> 6, cw0 = gidx & 63;
    uint4 w;
    w.x = *(const unsigned int*)(&tile[px * 130 + 2 * (cw0 + 0)]);
    w.y = *(const unsigned int*)(&tile[px * 130 + 2 * (cw0 + 1)]);
    w.z = *(const unsigned int*)(&tile[px * 130 + 2 * (cw0 + 2)]);
    w.w = *(const unsigned int*)(&tile[px * 130 + 2 * (cw0 + 3)]);
    *(uint4*)(dst + gidx) = w;
  }
}

// ---------------------------------------------------------------------------
// Kernel 1 (R8): REVERT to the verified R5 structure (AST=136 XOR-swizzled
// LDS, pmb[27*65], launch_bounds(256,3), lane=pixel prologue loads) with ONE
// change: the offmask PROLOGUE is software-pipelined 1 tap deep — tap t+1's
// A and B fragments are loaded into registers BEFORE tap t's MFMAs, so the
// ~200cy L2 latency hides under compute instead of being exposed per tap
// (prologue was ~35us for ~10us of issue work).  R7's chunk-major layout +
// (256,4) + LDS-staged prologue is fully reverted: it forced scratch spills
// (WRITE_SIZE 89->171MB, FETCH 27->61MB) and regressed 128.5 -> 158.4 us.
// ---------------------------------------------------------------------------
__global__ __launch_bounds__(256, 3)
void deform_main(const short* __restrict__ xt,
                 const short* __restrict__ Bt2f,
                 const short* __restrict__ Bt1f,
                 const float* __restrict__ offset_b,
                 const float* __restrict__ mask_b,
                 const float* __restrict__ bias,
                 float* __restrict__ out) {
  __shared__ short Ald[2][64 * AST];        // 34816 B
  __shared__ float pmb[27 * 65];            //  7020 B  (py[9],px[9],mk[9] x 64 px)

  const int tid  = threadIdx.x;
  const int lane = tid & 63;
  const int wv   = tid >> 6;
  const int q    = lane >> 4;
  const int m    = lane & 15;
  const int blk  = blockIdx.x;
  const int l    = (blk & 7) * BLK_PER_IMG + (blk >> 3);
  const int p0   = l * 64;
  const int b    = p0 / HW;
  const short* xtb = xt + (size_t)b * HW * 128;

  // ===== PROLOGUE: offset/mask conv, 1-tap software pipeline =====
  {
    const int p  = p0 + wv * 16 + m;
    const int hw = p % HW;
    const int h  = hw / IW, w_ = hw % IW;
    const short8 z = (short8){0, 0, 0, 0, 0, 0, 0, 0};

    floatx4 acc0 = (floatx4){0.f, 0.f, 0.f, 0.f};
    floatx4 acc1 = (floatx4){0.f, 0.f, 0.f, 0.f};

    short8 aC[4], b0C[4], b1C[4];
    bool valdC;
    // load tap 0
    {
      const int iy = h - 1, ix = w_ - 1;
      valdC = (iy >= 0 && iy < IH && ix >= 0 && ix < IW);
      const size_t pbase = valdC ? (size_t)(iy * IW + ix) * 128 : 0;
      #pragma unroll
      for (int kq = 0; kq < 4; ++kq) {
        aC[kq]  = *(const short8*)(xtb + pbase + kq * 32 + q * 8);
        b0C[kq] = *(const short8*)(Bt1f + (size_t)((0 * 4 + kq) * 2 + 0) * 512 + lane * 8);
        b1C[kq] = *(const short8*)(Bt1f + (size_t)((0 * 4 + kq) * 2 + 1) * 512 + lane * 8);
      }
    }

    #pragma unroll
    for (int tap = 0; tap < 9; ++tap) {
      short8 aN[4], b0N[4], b1N[4];
      bool valdN = false;
      if (tap < 8) {
        const int kh = (tap + 1) / 3, kw = (tap + 1) % 3;
        const int iy = h + kh - 1, ix = w_ + kw - 1;
        valdN = (iy >= 0 && iy < IH && ix >= 0 && ix < IW);
        const size_t pbase = valdN ? (size_t)(iy * IW + ix) * 128 : 0;
        #pragma unroll
        for (int kq = 0; kq < 4; ++kq) {
          aN[kq]  = *(const short8*)(xtb + pbase + kq * 32 + q * 8);
          b0N[kq] = *(const short8*)(Bt1f + (size_t)(((tap + 1) * 4 + kq) * 2 + 0) * 512 + lane * 8);
          b1N[kq] = *(const short8*)(Bt1f + (size_t)(((tap + 1) * 4 + kq) * 2 + 1) * 512 + lane * 8);
        }
      }
      #pragma unroll
      for (int kq = 0; kq < 4; ++kq) {
        short8 av = valdC ? aC[kq] : z;
        acc0 = __builtin_amdgcn_mfma_f32_16x16x32_bf16(av, b0C[kq], acc0, 0, 0, 0);
        acc1 = __builtin_amdgcn_mfma_f32_16x16x32_bf16(av, b1C[kq], acc1, 0, 0, 0);
      }
      valdC = valdN;
      #pragma unroll
      for (int kq = 0; kq < 4; ++kq) {
        aC[kq] = aN[kq]; b0C[kq] = b0N[kq]; b1C[kq] = b1N[kq];
      }
    }

    #pragma unroll
    for (int nl = 0; nl < 2; ++nl) {
      floatx4 ac = nl ? acc1 : acc0;
      int ch = nl * 16 + m;
      if (ch < 18) {
        int tap = ch >> 1, plane = ch & 1;
        float cb = offset_b[ch];
        #pragma unroll
        for (int r = 0; r < 4; ++r) {
          int col = wv * 16 + q * 4 + r;
          int hwp = (p0 + col) % HW;
          float base = plane ? (float)(hwp % IW + tap % 3 - 1)
                             : (float)(hwp / IW + tap / 3 - 1);
          pmb[(plane * 9 + tap) * 65 + col] = ac[r] + cb + base;
        }
      } else if (ch < 27) {
        int tap = ch - 18;
        float cb = mask_b[tap];
        #pragma unroll
        for (int r = 0; r < 4; ++r) {
          int col = wv * 16 + q * 4 + r;
          float v = ac[r] + cb;
          pmb[(18 + tap) * 65 + col] = 1.f / (1.f + expf(-v));
        }
      }
    }
  }
  __syncthreads();

  // ===== MAIN: cooperative-gather sampling + deformable GEMM (R5, verified)
  const int r8    = lane >> 3;              // pixel within group of 8
  const int ck    = lane & 7;               // chunk within 128B half-row
  const int ckoff = ck * 8;                 // shorts, folded into row ptrs
  const int row0  = wv * 16 + r8;           // pixel-group 0 row (local col)
  const int row1  = row0 + 8;               // pixel-group 1 row
  const int wk0   = (row0 >> 1) & 7;        // write swizzle keys
  const int wk1   = (row1 >> 1) & 7;
  const int wb0   = row0 * AST;
  const int wb1   = row1 * AST;
  const int rsw   = (m >> 1) & 7;           // MFMA-read swizzle key

  floatx4 acc[4][4];
  #pragma unroll
  for (int i = 0; i < 4; ++i)
    #pragma unroll
    for (int j = 0; j < 4; ++j) acc[i][j] = (floatx4){0.f, 0.f, 0.f, 0.f};

  // ---- stage tap 0 (cooperative) ----
  {
    float py0 = pmb[row0], px0 = pmb[9 * 65 + row0], mk0 = pmb[18 * 65 + row0];
    float py1 = pmb[row1], px1 = pmb[9 * 65 + row1], mk1 = pmb[18 * 65 + row1];
    Corner c0 = corner_setup(py0, px0, mk0, xtb, ckoff);
    Corner c1 = corner_setup(py1, px1, mk1, xtb, ckoff);
    short8 a0 = *(const short8*)(c0.r00),      a1 = *(const short8*)(c0.r01);
    short8 a2 = *(const short8*)(c0.r10),      a3 = *(const short8*)(c0.r11);
    short8 a4 = *(const short8*)(c0.r00 + 64), a5 = *(const short8*)(c0.r01 + 64);
    short8 a6 = *(const short8*)(c0.r10 + 64), a7 = *(const short8*)(c0.r11 + 64);
    short8 b0 = *(const short8*)(c1.r00),      b1 = *(const short8*)(c1.r01);
    short8 b2 = *(const short8*)(c1.r10),      b3 = *(const short8*)(c1.r11);
    short8 b4 = *(const short8*)(c1.r00 + 64), b5 = *(const short8*)(c1.r01 + 64);
    short8 b6 = *(const short8*)(c1.r10 + 64), b7 = *(const short8*)(c1.r11 + 64);
    *(short8*)(&Ald[0][wb0 + (ck ^ wk0) * 8])       = interp8(a0, a1, a2, a3, c0);
    *(short8*)(&Ald[0][wb0 + (8 + (ck ^ wk0)) * 8]) = interp8(a4, a5, a6, a7, c0);
    *(short8*)(&Ald[0][wb1 + (ck ^ wk1) * 8])       = interp8(b0, b1, b2, b3, c1);
    *(short8*)(&Ald[0][wb1 + (8 + (ck ^ wk1)) * 8]) = interp8(b4, b5, b6, b7, c1);
  }
  float pyN0 = pmb[1 * 65 + row0];
  float pxN0 = pmb[10 * 65 + row0];
  float mkN0 = pmb[19 * 65 + row0];
  float pyN1 = pmb[1 * 65 + row1];
  float pxN1 = pmb[10 * 65 + row1];
  float mkN1 = pmb[19 * 65 + row1];
  __syncthreads();

  for (int tap = 0; tap < 9; ++tap) {
    const short* bufr = Ald[tap & 1];
    short* const wbuf = Ald[(tap & 1) ^ 1];
    const bool nxt = (tap < 8);

    Corner c0, c1;
    if (nxt) {
      c0 = corner_setup(pyN0, pxN0, mkN0, xtb, ckoff);
      c1 = corner_setup(pyN1, pxN1, mkN1, xtb, ckoff);
    }
    if (tap < 7) {
      pyN0 = pmb[(tap + 2) * 65 + row0];
      pxN0 = pmb[(tap + 11) * 65 + row0];
      mkN0 = pmb[(tap + 20) * 65 + row0];
      pyN1 = pmb[(tap + 2) * 65 + row1];
      pxN1 = pmb[(tap + 11) * 65 + row1];
      mkN1 = pmb[(tap + 20) * 65 + row1];
    }

    // ---- B-frags kq0,kq1 + pixel-group-0 gathers in flight over kq0/kq1
    short8 bfA[4], bfB[4];
    #pragma unroll
    for (int nl = 0; nl < 4; ++nl) {
      bfA[nl] = *(const short8*)(Bt2f + (size_t)((tap * 4 + 0) * 16 + wv * 4 + nl) * 512 + lane * 8);
      bfB[nl] = *(const short8*)(Bt2f + (size_t)((tap * 4 + 1) * 16 + wv * 4 + nl) * 512 + lane * 8);
    }
    short8 g0, g1, g2, g3, g4, g5, g6, g7;
    if (nxt) {
      g0 = *(const short8*)(c0.r00);      g1 = *(const short8*)(c0.r01);
      g2 = *(const short8*)(c0.r10);      g3 = *(const short8*)(c0.r11);
      g4 = *(const short8*)(c0.r00 + 64); g5 = *(const short8*)(c0.r01 + 64);
      g6 = *(const short8*)(c0.r10 + 64); g7 = *(const short8*)(c0.r11 + 64);
    }
    // kq0
    {
      short8 af[4];
      #pragma unroll
      for (int mt = 0; mt < 4; ++mt)
        af[mt] = *(const short8*)(bufr + (mt * 16 + m) * AST + ((0 * 4 + q) ^ rsw) * 8);
      #pragma unroll
      for (int mt = 0; mt < 4; ++mt)
        #pragma unroll
        for (int nl = 0; nl < 4; ++nl)
          acc[mt][nl] = __builtin_amdgcn_mfma_f32_16x16x32_bf16(af[mt], bfA[nl], acc[mt][nl], 0, 0, 0);
    }
    // kq1
    {
      short8 af[4];
      #pragma unroll
      for (int mt = 0; mt < 4; ++mt)
        af[mt] = *(const short8*)(bufr + (mt * 16 + m) * AST + ((1 * 4 + q) ^ rsw) * 8);
      #pragma unroll
      for (int mt = 0; mt < 4; ++mt)
        #pragma unroll
        for (int nl = 0; nl < 4; ++nl)
          acc[mt][nl] = __builtin_amdgcn_mfma_f32_16x16x32_bf16(af[mt], bfB[nl], acc[mt][nl], 0, 0, 0);
    }
    // ---- B-frags kq2,kq3; interp pg0; pg1 gathers in flight over kq2/kq3
    short8 bfC[4], bfD[4];
    #pragma unroll
    for (int nl = 0; nl < 4; ++nl) {
      bfC[nl] = *(const short8*)(Bt2f + (size_t)((tap * 4 + 2) * 16 + wv * 4 + nl) * 512 + lane * 8);
      bfD[nl] = *(const short8*)(Bt2f + (size_t)((tap * 4 + 3) * 16 + wv * 4 + nl) * 512 + lane * 8);
    }
    if (nxt) {
      *(short8*)(&wbuf[wb0 + (ck ^ wk0) * 8])       = interp8(g0, g1, g2, g3, c0);
      *(short8*)(&wbuf[wb0 + (8 + (ck ^ wk0)) * 8]) = interp8(g4, g5, g6, g7, c0);
      g0 = *(const short8*)(c1.r00);      g1 = *(const short8*)(c1.r01);
      g2 = *(const short8*)(c1.r10);      g3 = *(const short8*)(c1.r11);
      g4 = *(const short8*)(c1.r00 + 64); g5 = *(const short8*)(c1.r01 + 64);
      g6 = *(const short8*)(c1.r10 + 64); g7 = *(const short8*)(c1.r11 + 64);
    }
    // kq2
    {
      short8 af[4];
      #pragma unroll
      for (int mt = 0; mt < 4; ++mt)
        af[mt] = *(const short8*)(bufr + (mt * 16 + m) * AST + ((2 * 4 + q) ^ rsw) * 8);
      #pragma unroll
      for (int mt = 0; mt < 4; ++mt)
        #pragma unroll
        for (int nl = 0; nl < 4; ++nl)
          acc[mt][nl] = __builtin_amdgcn_mfma_f32_16x16x32_bf16(af[mt], bfC[nl], acc[mt][nl], 0, 0, 0);
    }
    // kq3
    {
      short8 af[4];
      #pragma unroll
      for (int mt = 0; mt < 4; ++mt)
        af[mt] = *(const short8*)(bufr + (mt * 16 + m) * AST + ((3 * 4 + q) ^ rsw) * 8);
      #pragma unroll
      for (int mt = 0; mt < 4; ++mt)
        #pragma unroll
        for (int nl = 0; nl < 4; ++nl)
          acc[mt][nl] = __builtin_amdgcn_mfma_f32_16x16x32_bf16(af[mt], bfD[nl], acc[mt][nl], 0, 0, 0);
    }
    if (nxt) {
      *(short8*)(&wbuf[wb1 + (ck ^ wk1) * 8])       = interp8(g0, g1, g2, g3, c1);
      *(short8*)(&wbuf[wb1 + (8 + (ck ^ wk1)) * 8]) = interp8(g4, g5, g6, g7, c1);
      __syncthreads();
    }
  }

  // ---- epilogue: direct stores.  D: row=q*4+r -> px mt*16+q*4+r, col=m ----
  const int hw0 = p0 % HW;
  #pragma unroll
  for (int nl = 0; nl < 4; ++nl) {
    const int o = wv * 64 + nl * 16 + m;
    const float bs = bias[o];
    float* op = out + (size_t)(b * COUT + o) * HW + hw0;
    #pragma unroll
    for (int mt = 0; mt < 4; ++mt) {
      floatx4 v = acc[mt][nl];
      v[0] += bs; v[1] += bs; v[2] += bs; v[3] += bs;
      *(floatx4*)(op + mt * 16 + q * 4) = v;
    }
  }
}

// ---------------------------------------------------------------------------
extern "C" void kernel_launch(void* const* d_in, const int* in_sizes, int n_in,
                              void* d_out, int out_size, void* d_ws, size_t ws_size,
                              hipStream_t stream) {
  const float* x        = (const float*)d_in[0];
  const float* offset_w = (const float*)d_in[1];
  const float* offset_b = (const float*)d_in[2];
  const float* mask_w   = (const float*)d_in[3];
  const float* mask_b   = (const float*)d_in[4];
  const float* weight   = (const float*)d_in[5];
  const float* bias     = (const float*)d_in[6];
  float* out = (float*)d_out;

  char* ws = (char*)d_ws;
  const size_t XT_BYTES  = (size_t)NPIX * 128 * 2;        // 18,874,368
  const size_t BT2_BYTES = (size_t)9 * 4 * 16 * 512 * 2;  //    589,824
  short* xtp  = (short*)ws;
  short* Bt2f = (short*)(ws + XT_BYTES);
  short* Bt1f = (short*)(ws + XT_BYTES + BT2_BYTES);

  prep_and_transpose<<<dim3(TBLK + 324), dim3(256), 0, stream>>>(
      x, xtp, weight, offset_w, mask_w, Bt2f, Bt1f);
  deform_main<<<dim3(NPIX / 64), dim3(256), 0, stream>>>(
      xtp, Bt2f, Bt1f, offset_b, mask_b, bias, out);
}